// Round 1
// baseline (511.660 us; speedup 1.0000x reference)
//
#include <hip/hip_runtime.h>

// Problem constants (from reference)
#define BATCH   2048
#define SEQ     160     // input sequence stride
#define LOUT    128     // END - START
#define D_MODEL 256
#define NBINS   16
#define LN_EPS  1e-5f

__device__ __forceinline__ void fma4(float4& h, float s, const float4& w) {
    h.x = fmaf(s, w.x, h.x);
    h.y = fmaf(s, w.y, h.y);
    h.z = fmaf(s, w.z, h.z);
    h.w = fmaf(s, w.w, h.w);
}

// One wave (64 lanes) per (b, l) row; lane j owns d = 4j .. 4j+3.
// Block = 256 threads = 4 waves. Grid-stride over 2048*128 rows.
__global__ __launch_bounds__(256, 4)
void action_embedding_kernel(
    const int*   __restrict__ token_ids,      // (B, SEQ)
    const int*   __restrict__ action_actors,  // (B, SEQ)
    const int*   __restrict__ action_streets, // (B, SEQ)
    const float* __restrict__ legal_masks,    // (B, SEQ, NBINS)
    const float* __restrict__ actor_w,        // (2, D)
    const float* __restrict__ street_w,       // (4, D)
    const float* __restrict__ pos_w,          // (LOUT, D)
    const float* __restrict__ mlp_w,          // (NBINS, D)
    const float* __restrict__ mlp_b,          // (D,)
    const float* __restrict__ ln_g,           // (D,)
    const float* __restrict__ ln_b,           // (D,)
    float*       __restrict__ out)            // (B, LOUT, D)
{
    const int lane = threadIdx.x & 63;
    const int wave = threadIdx.x >> 6;   // 0..3
    const int d0   = lane << 2;          // 0,4,...,252

    // Hoist per-lane weight fragments into registers (amortized over the
    // grid-stride loop). 16 x float4 = 64 VGPRs.
    float4 w[NBINS];
#pragma unroll
    for (int k = 0; k < NBINS; ++k)
        w[k] = *reinterpret_cast<const float4*>(&mlp_w[k * D_MODEL + d0]);
    const float4 b4  = *reinterpret_cast<const float4*>(&mlp_b[d0]);
    const float4 g4  = *reinterpret_cast<const float4*>(&ln_g[d0]);
    const float4 lb4 = *reinterpret_cast<const float4*>(&ln_b[d0]);

    const int total   = BATCH * LOUT;            // 262144 rows
    const int wave_id = blockIdx.x * 4 + wave;
    const int nwaves  = gridDim.x * 4;

    for (int idx = wave_id; idx < total; idx += nwaves) {
        const int b = idx >> 7;       // idx / 128
        const int l = idx & 127;      // idx % 128
        const int in_off = b * SEQ + l;

        // 16 mask values (64 B, wave-uniform address -> broadcast loads)
        const float4* m4 = reinterpret_cast<const float4*>(&legal_masks[(size_t)in_off * NBINS]);
        const float4 m0 = m4[0], m1 = m4[1], m2 = m4[2], m3 = m4[3];

        // h = mlp_b + masks . mlp_w   (per-lane 4 columns)
        float4 h = b4;
        fma4(h, m0.x, w[0]);  fma4(h, m0.y, w[1]);
        fma4(h, m0.z, w[2]);  fma4(h, m0.w, w[3]);
        fma4(h, m1.x, w[4]);  fma4(h, m1.y, w[5]);
        fma4(h, m1.z, w[6]);  fma4(h, m1.w, w[7]);
        fma4(h, m2.x, w[8]);  fma4(h, m2.y, w[9]);
        fma4(h, m2.z, w[10]); fma4(h, m2.w, w[11]);
        fma4(h, m3.x, w[12]); fma4(h, m3.y, w[13]);
        fma4(h, m3.z, w[14]); fma4(h, m3.w, w[15]);

        // LayerNorm stats across 256 elements = 64 lanes x 4
        float s  = h.x + h.y + h.z + h.w;
        float ss = h.x * h.x + h.y * h.y + h.z * h.z + h.w * h.w;
#pragma unroll
        for (int off = 32; off > 0; off >>= 1) {
            s  += __shfl_xor(s, off);
            ss += __shfl_xor(ss, off);
        }
        const float mu  = s * (1.0f / D_MODEL);
        const float var = ss * (1.0f / D_MODEL) - mu * mu;
        const float rstd = rsqrtf(var + LN_EPS);

        // Scalar per-row metadata (wave-uniform broadcast loads)
        const int tok = token_ids[in_off];
        const int act = action_actors[in_off];
        const int str = action_streets[in_off];
        const float vfl = (tok >= 0) ? 1.0f : 0.0f;

        const float4 aw = *reinterpret_cast<const float4*>(&actor_w[act * D_MODEL + d0]);
        const float4 sw = *reinterpret_cast<const float4*>(&street_w[str * D_MODEL + d0]);
        const float4 pw = *reinterpret_cast<const float4*>(&pos_w[l * D_MODEL + d0]);

        float4 o;
        o.x = (fmaxf((h.x - mu) * rstd * g4.x + lb4.x, 0.0f) + aw.x + sw.x + pw.x) * vfl;
        o.y = (fmaxf((h.y - mu) * rstd * g4.y + lb4.y, 0.0f) + aw.y + sw.y + pw.y) * vfl;
        o.z = (fmaxf((h.z - mu) * rstd * g4.z + lb4.z, 0.0f) + aw.z + sw.z + pw.z) * vfl;
        o.w = (fmaxf((h.w - mu) * rstd * g4.w + lb4.w, 0.0f) + aw.w + sw.w + pw.w) * vfl;

        *reinterpret_cast<float4*>(&out[(size_t)idx * D_MODEL + d0]) = o;
    }
}

extern "C" void kernel_launch(void* const* d_in, const int* in_sizes, int n_in,
                              void* d_out, int out_size, void* d_ws, size_t ws_size,
                              hipStream_t stream) {
    const int*   token_ids      = (const int*)  d_in[0];
    const int*   action_actors  = (const int*)  d_in[1];
    const int*   action_streets = (const int*)  d_in[2];
    const float* legal_masks    = (const float*)d_in[3];
    const float* actor_w        = (const float*)d_in[4];
    const float* street_w       = (const float*)d_in[5];
    const float* pos_w          = (const float*)d_in[6];
    const float* mlp_w          = (const float*)d_in[7];
    const float* mlp_b          = (const float*)d_in[8];
    const float* ln_g           = (const float*)d_in[9];
    const float* ln_b           = (const float*)d_in[10];
    float* out = (float*)d_out;

    dim3 grid(2048), block(256);
    hipLaunchKernelGGL(action_embedding_kernel, grid, block, 0, stream,
                       token_ids, action_actors, action_streets, legal_masks,
                       actor_w, street_w, pos_w, mlp_w, mlp_b, ln_g, ln_b, out);
}